// Round 4
// baseline (791.892 us; speedup 1.0000x reference)
//
#include <hip/hip_runtime.h>
#include <hip/hip_bf16.h>

#define NN 6607
#define HH 64
#define TT 3
#define EE 1000000

typedef __attribute__((ext_vector_type(8))) short bf16x8;
typedef __attribute__((ext_vector_type(4))) short short4v;
typedef __attribute__((ext_vector_type(4))) float f32x4;
typedef __attribute__((ext_vector_type(4))) int i32x4;

// ---------------- fused prep: zero(degI+cursor) + Wrec->bf16 + x_init copy ----------------

__global__ void prep_kernel(const float* __restrict__ wrec, short* __restrict__ wrecb,
                            const float* __restrict__ emb, float* __restrict__ o_xinit,
                            int* __restrict__ zero_base) {
    int i = blockIdx.x * 256 + threadIdx.x;
    // zero 158592 B = 9912 int4
    if (i < 9912) ((i32x4*)zero_base)[i] = (i32x4){0, 0, 0, 0};
    // x_init copy: 105712 f32x4
    if (i < 105712) ((f32x4*)o_xinit)[i] = ((const f32x4*)emb)[i];
    // wconv: 3*6607*64 = 1268544 floats = 317136 f32x4 chunks
    if (i < 317136) {
        f32x4 v = ((const f32x4*)wrec)[i];
        short4v s;
        s[0] = (short)__bfloat16_as_ushort(__float2bfloat16(v[0]));
        s[1] = (short)__bfloat16_as_ushort(__float2bfloat16(v[1]));
        s[2] = (short)__bfloat16_as_ushort(__float2bfloat16(v[2]));
        s[3] = (short)__bfloat16_as_ushort(__float2bfloat16(v[3]));
        ((short4v*)wrecb)[i] = s;
    }
}

// ---------------- CSR build ----------------

__global__ void hist_kernel(const int* __restrict__ ei, int* __restrict__ degI) {
    int e = blockIdx.x * 256 + threadIdx.x;
    int t = blockIdx.y;
    if (e >= EE) return;
    int dst = ei[t * 2 * EE + EE + e];
    atomicAdd(&degI[t * NN + dst], 1);
}

__global__ void scan_kernel(const int* __restrict__ degI, int* __restrict__ rowptr) {
    int t = blockIdx.x;
    __shared__ int sh[256];
    __shared__ int carry_sh;
    int tid = threadIdx.x;
    if (tid == 0) carry_sh = 0;
    __syncthreads();
    for (int base = 0; base < NN; base += 256) {
        int i = base + tid;
        int v = (i < NN) ? degI[t * NN + i] : 0;
        sh[tid] = v;
        __syncthreads();
        for (int off = 1; off < 256; off <<= 1) {
            int x = (tid >= off) ? sh[tid - off] : 0;
            __syncthreads();
            sh[tid] += x;
            __syncthreads();
        }
        int incl = sh[tid];
        int carry = carry_sh;
        if (i < NN) rowptr[t * (NN + 1) + i] = carry + incl - v;  // exclusive
        __syncthreads();
        if (tid == 255) carry_sh = carry + incl;
        __syncthreads();
    }
    if (tid == 0) rowptr[t * (NN + 1) + NN] = carry_sh;  // == EE
}

__global__ void fill_kernel(const int* __restrict__ ei, const int* __restrict__ rowptr,
                            int* __restrict__ cursor, int* __restrict__ csr) {
    int e = blockIdx.x * 256 + threadIdx.x;
    int t = blockIdx.y;
    if (e >= EE) return;
    int src = ei[t * 2 * EE + e];
    int dst = ei[t * 2 * EE + EE + e];
    int pos = atomicAdd(&cursor[t * NN + dst], 1);
    csr[t * EE + rowptr[t * (NN + 1) + dst] + pos] = src;
}

// ---------------- SAGE layer ----------------
// block = 256 threads = 4 waves, each wave owns one node; lane = channel.
// matvec via LDS-broadcast float4 (no shfl): out[h]=b[h]+sum_k mean[k]*Wl[h][k]+xi[k]*Wr[h][k]

template <int LAYER>
__global__ void sage_kernel(const float* __restrict__ x_all,
                            const int* __restrict__ rowptr, const int* __restrict__ csr,
                            const float* __restrict__ W_l, const float* __restrict__ b_l,
                            const float* __restrict__ W_r,
                            float* __restrict__ y, __hip_bfloat16* __restrict__ yb) {
    int t = blockIdx.y;
    __shared__ float wl[64][68];   // row-major, +4 pad keeps rows 16B-aligned
    __shared__ float wr[64][68];
    __shared__ float mean_s[4][64];
    __shared__ float xi_s[4][64];
    const f32x4* Wl4 = (const f32x4*)(W_l + t * 4096);
    const f32x4* Wr4 = (const f32x4*)(W_r + t * 4096);
    for (int c = threadIdx.x; c < 1024; c += 256) {
        int h = c >> 4, k = (c & 15) << 2;
        *(f32x4*)&wl[h][k] = Wl4[c];
        *(f32x4*)&wr[h][k] = Wr4[c];
    }
    __syncthreads();

    int lane = threadIdx.x & 63;
    int widx = threadIdx.x >> 6;
    int i = blockIdx.x * 4 + widx;
    if (i >= NN) return;

    const float* x = x_all + (LAYER == 2 ? (size_t)t * NN * HH : 0);
    int rp0 = rowptr[t * (NN + 1) + i];
    int rp1 = rowptr[t * (NN + 1) + i + 1];
    const int* cs = csr + t * EE;

    float a0 = 0.f, a1 = 0.f, a2 = 0.f, a3 = 0.f;
    float a4 = 0.f, a5 = 0.f, a6 = 0.f, a7 = 0.f;
    int e = rp0;
    for (; e + 8 <= rp1; e += 8) {
        int s0 = cs[e], s1 = cs[e + 1], s2 = cs[e + 2], s3 = cs[e + 3];
        int s4 = cs[e + 4], s5 = cs[e + 5], s6 = cs[e + 6], s7 = cs[e + 7];
        a0 += x[s0 * 64 + lane];
        a1 += x[s1 * 64 + lane];
        a2 += x[s2 * 64 + lane];
        a3 += x[s3 * 64 + lane];
        a4 += x[s4 * 64 + lane];
        a5 += x[s5 * 64 + lane];
        a6 += x[s6 * 64 + lane];
        a7 += x[s7 * 64 + lane];
    }
    for (; e < rp1; ++e) a0 += x[cs[e] * 64 + lane];
    float acc = ((a0 + a1) + (a2 + a3)) + ((a4 + a5) + (a6 + a7));

    int d = rp1 - rp0;
    float mean = acc / (float)(d > 1 ? d : 1);
    float xi = x[i * 64 + lane];

    mean_s[widx][lane] = mean;
    xi_s[widx][lane] = xi;
    // same-wave write->read; compiler inserts lgkmcnt wait, no barrier needed

    float out = b_l[t * 64 + lane];
    #pragma unroll 4
    for (int k0 = 0; k0 < 64; k0 += 4) {
        f32x4 m4 = *(const f32x4*)&mean_s[widx][k0];
        f32x4 x4 = *(const f32x4*)&xi_s[widx][k0];
        f32x4 l4 = *(const f32x4*)&wl[lane][k0];
        f32x4 r4 = *(const f32x4*)&wr[lane][k0];
        out += m4[0] * l4[0] + m4[1] * l4[1] + m4[2] * l4[2] + m4[3] * l4[3];
        out += x4[0] * r4[0] + x4[1] * r4[1] + x4[2] * r4[2] + x4[3] * r4[3];
    }
    out = fmaxf(out, 0.f);
    y[(size_t)t * NN * HH + i * 64 + lane] = out;
    if (LAYER == 2) yb[(size_t)t * NN * HH + i * 64 + lane] = __float2bfloat16(out);
}

// ---------------- reconstruction: recon[t] = h2[t] @ Wrec[t]^T + brec[t] ----------------
// Swapped-operand MFMA: D = mfma(Wrec_frag, h2_frag) -> lane l holds
// recon[i0 + (l&15)][j0 + (l>>4)*4 + q], q=0..3 -> direct per-lane float4 row stores
// (4 lanes per row form 64B contiguous; block covers rows fully -> L2 merges sectors).
// Block tile: 32 rows x 1024 cols; wave (w>>1) = row half, (w&1) = col half (16x512/wave).

__global__ void recon_kernel(const short* __restrict__ h2b, const short* __restrict__ wrecb,
                             const float* __restrict__ brec, float* __restrict__ out) {
    constexpr int NI = (NN + 31) / 32;     // 207
    constexpr int NJ = (NN + 1023) / 1024; // 7
    int bid = blockIdx.x;
    int t = bid / (NI * NJ);
    int rem = bid % (NI * NJ);
    int jc = rem / NI;
    int it = rem % NI;

    int lane = threadIdx.x & 63;
    int wid = threadIdx.x >> 6;
    int r = lane & 15;
    int kb = (lane >> 4) * 8;
    int rbase = (lane >> 4) * 4;

    int i0 = it * 32 + (wid >> 1) * 16;
    int jbase = jc * 1024 + (wid & 1) * 512;

    const short* A = h2b + (size_t)t * NN * HH;
    const short* B = wrecb + (size_t)t * NN * HH;

    int row = i0 + r;                       // may exceed NN-1 on last strip (A is padded)
    bf16x8 a0 = *(const bf16x8*)(A + (size_t)row * 64 + kb);
    bf16x8 a1 = *(const bf16x8*)(A + (size_t)row * 64 + kb + 32);

    bool rowok = (row < NN);
    size_t orow = (size_t)t * NN * NN + (size_t)row * NN;
    const float* br = brec + t * NN;

    #pragma unroll 4
    for (int jt = 0; jt < 32; ++jt) {
        int j0 = jbase + jt * 16;
        if (j0 >= NN) break;
        bf16x8 b0 = *(const bf16x8*)(B + (size_t)(j0 + r) * 64 + kb);
        bf16x8 b1 = *(const bf16x8*)(B + (size_t)(j0 + r) * 64 + kb + 32);
        f32x4 acc = {0.f, 0.f, 0.f, 0.f};
        acc = __builtin_amdgcn_mfma_f32_16x16x32_bf16(b0, a0, acc, 0, 0, 0);
        acc = __builtin_amdgcn_mfma_f32_16x16x32_bf16(b1, a1, acc, 0, 0, 0);
        int c0 = j0 + rbase;
        if (rowok) {
            if (j0 + 16 <= NN) {
                f32x4 w = {acc[0] + br[c0], acc[1] + br[c0 + 1],
                           acc[2] + br[c0 + 2], acc[3] + br[c0 + 3]};
                *(f32x4*)(out + orow + c0) = w;
            } else {
                #pragma unroll
                for (int q = 0; q < 4; ++q)
                    if (c0 + q < NN) out[orow + c0 + q] = acc[q] + br[c0 + q];
            }
        }
    }
}

// ---------------- launch ----------------

extern "C" void kernel_launch(void* const* d_in, const int* in_sizes, int n_in,
                              void* d_out, int out_size, void* d_ws, size_t ws_size,
                              hipStream_t stream) {
    const float* emb  = (const float*)d_in[0];
    const int*   ei   = (const int*)d_in[1];
    const float* W1l  = (const float*)d_in[2];
    const float* b1   = (const float*)d_in[3];
    const float* W1r  = (const float*)d_in[4];
    const float* W2l  = (const float*)d_in[5];
    const float* b2   = (const float*)d_in[6];
    const float* W2r  = (const float*)d_in[7];
    const float* Wrec = (const float*)d_in[8];
    const float* brec = (const float*)d_in[9];

    char* ws = (char*)d_ws;
    int*   degI   = (int*)(ws + 0);                       // 79284 -> pad 79296
    int*   cursor = (int*)(ws + 79296);                   // 79284 -> pad 79296 (zeroed with degI)
    int*   rowptr = (int*)(ws + 158592);                  // 79296 (fully overwritten by scan)
    int*   csr    = (int*)(ws + 237888);                  // 12000000
    float* h1     = (float*)(ws + 12237888);              // 5074176
    short* h2b    = (short*)(ws + 17312064);              // (3*6607*64+4096)*2 = 2545280
    short* wrecb  = (short*)(ws + 19857344);              // 2545280 -> end 22402624

    float* o_emb   = (float*)d_out;                        // [T][N][H]
    float* o_recon = o_emb + (size_t)TT * NN * HH;         // [T][N][N]
    float* o_xinit = o_recon + (size_t)TT * NN * NN;       // [N][H]

    // fused prep: zero(degI+cursor), Wrec->bf16, x_init copy
    prep_kernel<<<(317136 + 255) / 256, 256, 0, stream>>>(Wrec, wrecb, emb, o_xinit, (int*)ws);

    dim3 egrid((EE + 255) / 256, TT);
    hist_kernel<<<egrid, 256, 0, stream>>>(ei, degI);
    scan_kernel<<<TT, 256, 0, stream>>>(degI, rowptr);
    fill_kernel<<<egrid, 256, 0, stream>>>(ei, rowptr, cursor, csr);

    dim3 sgrid((NN + 3) / 4, TT);
    sage_kernel<1><<<sgrid, 256, 0, stream>>>(emb, rowptr, csr, W1l, b1, W1r, h1, nullptr);
    sage_kernel<2><<<sgrid, 256, 0, stream>>>(h1, rowptr, csr, W2l, b2, W2r, o_emb,
                                              (__hip_bfloat16*)h2b);

    constexpr int NI = (NN + 31) / 32;     // 207
    constexpr int NJ = (NN + 1023) / 1024; // 7
    int rblocks = NI * NJ * TT;            // 4347
    recon_kernel<<<rblocks, 256, 0, stream>>>(h2b, wrecb, brec, o_recon);
}

// Round 5
// 688.492 us; speedup vs baseline: 1.1502x; 1.1502x over previous
//
#include <hip/hip_runtime.h>
#include <hip/hip_bf16.h>

#define NN 6607
#define HH 64
#define TT 3
#define EE 1000000

typedef __attribute__((ext_vector_type(8))) short bf16x8;
typedef __attribute__((ext_vector_type(4))) short short4v;
typedef __attribute__((ext_vector_type(4))) float f32x4;
typedef __attribute__((ext_vector_type(4))) int i32x4;

// ---------------- fused prep: zero(degI+cursor) + Wrec->bf16 + x_init copy ----------------

__global__ void prep_kernel(const float* __restrict__ wrec, short* __restrict__ wrecb,
                            const float* __restrict__ emb, float* __restrict__ o_xinit,
                            int* __restrict__ zero_base) {
    int i = blockIdx.x * 256 + threadIdx.x;
    if (i < 9912) ((i32x4*)zero_base)[i] = (i32x4){0, 0, 0, 0};
    if (i < 105712) ((f32x4*)o_xinit)[i] = ((const f32x4*)emb)[i];
    if (i < 317136) {
        f32x4 v = ((const f32x4*)wrec)[i];
        short4v s;
        s[0] = (short)__bfloat16_as_ushort(__float2bfloat16(v[0]));
        s[1] = (short)__bfloat16_as_ushort(__float2bfloat16(v[1]));
        s[2] = (short)__bfloat16_as_ushort(__float2bfloat16(v[2]));
        s[3] = (short)__bfloat16_as_ushort(__float2bfloat16(v[3]));
        ((short4v*)wrecb)[i] = s;
    }
}

// ---------------- CSR build ----------------

__global__ void hist_kernel(const int* __restrict__ ei, int* __restrict__ degI) {
    int e = blockIdx.x * 256 + threadIdx.x;
    int t = blockIdx.y;
    if (e >= EE) return;
    int dst = ei[t * 2 * EE + EE + e];
    atomicAdd(&degI[t * NN + dst], 1);
}

__global__ void scan_kernel(const int* __restrict__ degI, int* __restrict__ rowptr) {
    int t = blockIdx.x;
    __shared__ int sh[256];
    __shared__ int carry_sh;
    int tid = threadIdx.x;
    if (tid == 0) carry_sh = 0;
    __syncthreads();
    for (int base = 0; base < NN; base += 256) {
        int i = base + tid;
        int v = (i < NN) ? degI[t * NN + i] : 0;
        sh[tid] = v;
        __syncthreads();
        for (int off = 1; off < 256; off <<= 1) {
            int x = (tid >= off) ? sh[tid - off] : 0;
            __syncthreads();
            sh[tid] += x;
            __syncthreads();
        }
        int incl = sh[tid];
        int carry = carry_sh;
        if (i < NN) rowptr[t * (NN + 1) + i] = carry + incl - v;  // exclusive
        __syncthreads();
        if (tid == 255) carry_sh = carry + incl;
        __syncthreads();
    }
    if (tid == 0) rowptr[t * (NN + 1) + NN] = carry_sh;  // == EE
}

__global__ void fill_kernel(const int* __restrict__ ei, const int* __restrict__ rowptr,
                            int* __restrict__ cursor, int* __restrict__ csr) {
    int e = blockIdx.x * 256 + threadIdx.x;
    int t = blockIdx.y;
    if (e >= EE) return;
    int src = ei[t * 2 * EE + e];
    int dst = ei[t * 2 * EE + EE + e];
    int pos = atomicAdd(&cursor[t * NN + dst], 1);
    csr[t * EE + rowptr[t * (NN + 1) + dst] + pos] = src;
}

// ---------------- SAGE layer ----------------

template <int LAYER>
__global__ void sage_kernel(const float* __restrict__ x_all,
                            const int* __restrict__ rowptr, const int* __restrict__ csr,
                            const float* __restrict__ W_l, const float* __restrict__ b_l,
                            const float* __restrict__ W_r,
                            float* __restrict__ y, __hip_bfloat16* __restrict__ yb) {
    int t = blockIdx.y;
    __shared__ float wl[64][68];
    __shared__ float wr[64][68];
    __shared__ float mean_s[4][64];
    __shared__ float xi_s[4][64];
    const f32x4* Wl4 = (const f32x4*)(W_l + t * 4096);
    const f32x4* Wr4 = (const f32x4*)(W_r + t * 4096);
    for (int c = threadIdx.x; c < 1024; c += 256) {
        int h = c >> 4, k = (c & 15) << 2;
        *(f32x4*)&wl[h][k] = Wl4[c];
        *(f32x4*)&wr[h][k] = Wr4[c];
    }
    __syncthreads();

    int lane = threadIdx.x & 63;
    int widx = threadIdx.x >> 6;
    int i = blockIdx.x * 4 + widx;
    if (i >= NN) return;

    const float* x = x_all + (LAYER == 2 ? (size_t)t * NN * HH : 0);
    int rp0 = rowptr[t * (NN + 1) + i];
    int rp1 = rowptr[t * (NN + 1) + i + 1];
    const int* cs = csr + t * EE;

    float a0 = 0.f, a1 = 0.f, a2 = 0.f, a3 = 0.f;
    float a4 = 0.f, a5 = 0.f, a6 = 0.f, a7 = 0.f;
    int e = rp0;
    for (; e + 8 <= rp1; e += 8) {
        int s0 = cs[e], s1 = cs[e + 1], s2 = cs[e + 2], s3 = cs[e + 3];
        int s4 = cs[e + 4], s5 = cs[e + 5], s6 = cs[e + 6], s7 = cs[e + 7];
        a0 += x[s0 * 64 + lane];
        a1 += x[s1 * 64 + lane];
        a2 += x[s2 * 64 + lane];
        a3 += x[s3 * 64 + lane];
        a4 += x[s4 * 64 + lane];
        a5 += x[s5 * 64 + lane];
        a6 += x[s6 * 64 + lane];
        a7 += x[s7 * 64 + lane];
    }
    for (; e < rp1; ++e) a0 += x[cs[e] * 64 + lane];
    float acc = ((a0 + a1) + (a2 + a3)) + ((a4 + a5) + (a6 + a7));

    int d = rp1 - rp0;
    float mean = acc / (float)(d > 1 ? d : 1);
    float xi = x[i * 64 + lane];

    mean_s[widx][lane] = mean;
    xi_s[widx][lane] = xi;

    float out = b_l[t * 64 + lane];
    #pragma unroll 4
    for (int k0 = 0; k0 < 64; k0 += 4) {
        f32x4 m4 = *(const f32x4*)&mean_s[widx][k0];
        f32x4 x4 = *(const f32x4*)&xi_s[widx][k0];
        f32x4 l4 = *(const f32x4*)&wl[lane][k0];
        f32x4 r4 = *(const f32x4*)&wr[lane][k0];
        out += m4[0] * l4[0] + m4[1] * l4[1] + m4[2] * l4[2] + m4[3] * l4[3];
        out += x4[0] * r4[0] + x4[1] * r4[1] + x4[2] * r4[2] + x4[3] * r4[3];
    }
    out = fmaxf(out, 0.f);
    y[(size_t)t * NN * HH + i * 64 + lane] = out;
    if (LAYER == 2) yb[(size_t)t * NN * HH + i * 64 + lane] = __float2bfloat16(out);
}

// ---------------- reconstruction: recon[t] = h2[t] @ Wrec[t]^T + brec[t] ----------------
// One block = 16-row strip x full width. 26 chunks of 256 cols, double-buffered LDS:
// per iteration, cooperative aligned stores of chunk c-1 (issued first, fire-and-forget
// under compute) overlap MFMA+LDS fill of chunk c; one barrier per chunk.
// mfma(a,b): lane l holds recon[i0+(l>>4)*4+q][j0+(l&15)] -> LDS scalar writes (2-way, free).
// Store phase: 4 passes x 4 rows, each row = 64 lanes x f32x4 = 1KB contiguous.

__global__ void recon_kernel(const short* __restrict__ h2b, const short* __restrict__ wrecb,
                             const float* __restrict__ brec, float* __restrict__ out) {
    constexpr int NI = (NN + 15) / 16;   // 413 strips
    constexpr int NCH = 26;              // chunks of 256 cols (25 full + 207 tail)
    __shared__ float buf[2][16][260];

    int bid = blockIdx.x;
    int t = bid / NI;
    int it = bid % NI;
    int i0 = it * 16;

    int tid = threadIdx.x;
    int lane = tid & 63;
    int w = tid >> 6;
    int r = lane & 15;
    int kb = (lane >> 4) * 8;
    int rbase = (lane >> 4) * 4;

    const short* A = h2b + (size_t)t * NN * HH;
    const short* B = wrecb + (size_t)t * NN * HH;
    const float* br = brec + t * NN;
    size_t obase = (size_t)t * NN * NN;

    bf16x8 a0 = *(const bf16x8*)(A + (size_t)(i0 + r) * 64 + kb);
    bf16x8 a1 = *(const bf16x8*)(A + (size_t)(i0 + r) * 64 + kb + 32);

    // store-phase thread mapping
    int srow_base = tid >> 6;        // +4 per pass -> rows 0..15
    int scol = (tid & 63) << 2;      // 0..252

    auto compute = [&](int chunk, int bi) {
        int jbase = chunk * 256 + w * 64;
        #pragma unroll
        for (int jt = 0; jt < 4; ++jt) {
            int j0 = jbase + jt * 16;
            bf16x8 b0 = *(const bf16x8*)(B + (size_t)(j0 + r) * 64 + kb);
            bf16x8 b1 = *(const bf16x8*)(B + (size_t)(j0 + r) * 64 + kb + 32);
            f32x4 acc = {0.f, 0.f, 0.f, 0.f};
            acc = __builtin_amdgcn_mfma_f32_16x16x32_bf16(a0, b0, acc, 0, 0, 0);
            acc = __builtin_amdgcn_mfma_f32_16x16x32_bf16(a1, b1, acc, 0, 0, 0);
            int jloc = w * 64 + jt * 16 + r;
            #pragma unroll
            for (int q = 0; q < 4; ++q) buf[bi][rbase + q][jloc] = acc[q];
        }
    };

    auto store = [&](int chunk, int bi) {
        int colg = chunk * 256 + scol;
        #pragma unroll
        for (int p = 0; p < 4; ++p) {
            int rloc = p * 4 + srow_base;
            int row = i0 + rloc;
            f32x4 v = *(const f32x4*)&buf[bi][rloc][scol];
            if (row < NN && colg < NN) {
                float* pp = out + obase + (size_t)row * NN + colg;
                if (colg + 4 <= NN) {
                    f32x4 wv = {v[0] + br[colg], v[1] + br[colg + 1],
                                v[2] + br[colg + 2], v[3] + br[colg + 3]};
                    *(f32x4*)pp = wv;
                } else {
                    pp[0] = v[0] + br[colg];
                    if (colg + 1 < NN) pp[1] = v[1] + br[colg + 1];
                    if (colg + 2 < NN) pp[2] = v[2] + br[colg + 2];
                }
            }
        }
    };

    compute(0, 0);
    __syncthreads();
    for (int c = 1; c < NCH; ++c) {
        store(c - 1, (c - 1) & 1);   // issued first: HBM stores drain under compute
        compute(c, c & 1);
        __syncthreads();
    }
    store(NCH - 1, (NCH - 1) & 1);
}

// ---------------- launch ----------------

extern "C" void kernel_launch(void* const* d_in, const int* in_sizes, int n_in,
                              void* d_out, int out_size, void* d_ws, size_t ws_size,
                              hipStream_t stream) {
    const float* emb  = (const float*)d_in[0];
    const int*   ei   = (const int*)d_in[1];
    const float* W1l  = (const float*)d_in[2];
    const float* b1   = (const float*)d_in[3];
    const float* W1r  = (const float*)d_in[4];
    const float* W2l  = (const float*)d_in[5];
    const float* b2   = (const float*)d_in[6];
    const float* W2r  = (const float*)d_in[7];
    const float* Wrec = (const float*)d_in[8];
    const float* brec = (const float*)d_in[9];

    char* ws = (char*)d_ws;
    int*   degI   = (int*)(ws + 0);                       // 79284 -> pad 79296
    int*   cursor = (int*)(ws + 79296);                   // 79284 -> pad 79296 (zeroed with degI)
    int*   rowptr = (int*)(ws + 158592);                  // 79296 (fully overwritten by scan)
    int*   csr    = (int*)(ws + 237888);                  // 12000000
    float* h1     = (float*)(ws + 12237888);              // 5074176
    short* h2b    = (short*)(ws + 17312064);              // (3*6607*64+4096)*2 = 2545280
    short* wrecb  = (short*)(ws + 19857344);              // 2545280 -> end 22402624

    float* o_emb   = (float*)d_out;                        // [T][N][H]
    float* o_recon = o_emb + (size_t)TT * NN * HH;         // [T][N][N]
    float* o_xinit = o_recon + (size_t)TT * NN * NN;       // [N][H]

    prep_kernel<<<(317136 + 255) / 256, 256, 0, stream>>>(Wrec, wrecb, emb, o_xinit, (int*)ws);

    dim3 egrid((EE + 255) / 256, TT);
    hist_kernel<<<egrid, 256, 0, stream>>>(ei, degI);
    scan_kernel<<<TT, 256, 0, stream>>>(degI, rowptr);
    fill_kernel<<<egrid, 256, 0, stream>>>(ei, rowptr, cursor, csr);

    dim3 sgrid((NN + 3) / 4, TT);
    sage_kernel<1><<<sgrid, 256, 0, stream>>>(emb, rowptr, csr, W1l, b1, W1r, h1, nullptr);
    sage_kernel<2><<<sgrid, 256, 0, stream>>>(h1, rowptr, csr, W2l, b2, W2r, o_emb,
                                              (__hip_bfloat16*)h2b);

    constexpr int NI = (NN + 15) / 16;   // 413
    int rblocks = NI * TT;               // 1239
    recon_kernel<<<rblocks, 256, 0, stream>>>(h2b, wrecb, brec, o_recon);
}